// Round 6
// baseline (111.494 us; speedup 1.0000x reference)
//
#include <hip/hip_runtime.h>
#include <cstdint>
#include <cstddef>

// Problem constants
#define NB 2
#define NF 8
#define NS 4
#define NK 90      // real K (dirs per shell)
#define NP 642     // grid vertices
#define NXYZ 1728  // 12*12*12
#define MT 64      // p-tile
#define PTILES 11  // ceil(642/64)
#define NG 108     // xyz 16-groups (1728/16)
#define XT_TASKS (64 * NG * 3)          // 20736 x-fragment blocks (1 KB each)
#define WT_TASKS (NS * PTILES * 4 * 3)  // 528 W-fragment blocks

typedef __attribute__((ext_vector_type(8))) __bf16 bf16x8;
typedef __attribute__((ext_vector_type(4))) float f32x4;
typedef __attribute__((ext_vector_type(4))) uint32_t u32x4;

// RNE pack of two f32 -> u32 holding 2 bf16
__device__ __forceinline__ uint32_t pack2bf(float a, float b) {
    uint32_t ua = __builtin_bit_cast(uint32_t, a);
    uint32_t ub = __builtin_bit_cast(uint32_t, b);
    ua += 0x7FFFu + ((ua >> 16) & 1u);
    ub += 0x7FFFu + ((ub >> 16) & 1u);
    return (ua >> 16) | (ub & 0xFFFF0000u);
}

// ============ Kernel 1: pack x and W into MFMA-fragment-order bf16 blocks.
// Block t (1 KB): 64 lanes x 16 B. Lane (lr=lane&15, lg=lane>>4) holds
// bf16[8] = operand row lr, k = kk*32 + lg*8 .. +8.
// x tasks: t = (e*108 + g)*3 + kk, e = (b*8+f)*4 + s.
// W tasks: XT + ((s*11 + pt)*4 + ni)*3 + kk.
__global__ __launch_bounds__(256) void prep_frag(
    const float* __restrict__ x, const float* __restrict__ Wm,
    uint32_t* __restrict__ ws)
{
    const int tid  = (int)threadIdx.x;
    const int lane = tid & 63;
    const int lr = lane & 15, lg = lane >> 4;
    const int task = (int)blockIdx.x * 4 + (tid >> 6);

    float v[8];
    if (task < XT_TASKS) {
        int t = task;
        const int kk = t % 3;   t /= 3;
        const int g  = t % NG;  t /= NG;
        const int e  = t;                  // 0..63
        const int s = e & 3, bf = e >> 2;
        const float* src = x + (size_t)bf * (NS * NK * NXYZ)
                             + (size_t)s * (NK * NXYZ) + g * 16 + lr;
        #pragma unroll
        for (int j = 0; j < 8; ++j) {
            const int k = kk * 32 + lg * 8 + j;
            v[j] = (k < NK) ? src[(size_t)k * NXYZ] : 0.f;
        }
    } else {
        int t = task - XT_TASKS;
        const int kk = t % 3;      t /= 3;
        const int ni = t % 4;      t /= 4;
        const int pt = t % PTILES; t /= PTILES;
        const int s  = t;                  // 0..3
        const int p = pt * MT + ni * 16 + lr;
        const float* src = Wm + (size_t)s * (NK * NP) + p;
        #pragma unroll
        for (int j = 0; j < 8; ++j) {
            const int k = kk * 32 + lg * 8 + j;
            v[j] = (k < NK && p < NP) ? src[(size_t)k * NP] : 0.f;
        }
    }
    u32x4 u;
    u.x = pack2bf(v[0], v[1]);
    u.y = pack2bf(v[2], v[3]);
    u.z = pack2bf(v[4], v[5]);
    u.w = pack2bf(v[6], v[7]);
    *(u32x4*)((char*)ws + (size_t)task * 1024 + lane * 16) = u;
}

// ============ Kernel 2: persistent-wave GEMM. One wave = (e, n32) keeps its
// 6 B-frags in regs and loops all 11 p-tiles, double-buffering the 12 A-frags
// (prefetch pt+1 under MFMA of pt) and streaming 8 dwordx4 NT stores/iter.
__global__ __launch_bounds__(64, 3) void gemm_loop(
    const uint32_t* __restrict__ ws, float* __restrict__ y)
{
    const int lane = (int)threadIdx.x & 63;
    const int lr = lane & 15, lg = lane >> 4;
    int t = (int)blockIdx.x;
    const int n32 = t % 54;  t /= 54;
    const int e = t;                        // 0..63
    const int s = e & 3, bfi = e >> 2;
    const int b = bfi >> 3, f = bfi & 7;

    const char* lbase = (const char*)ws + (size_t)lane * 16;
    const char* xb = lbase + (size_t)((e * NG + n32 * 2) * 3) * 1024;
    const char* ab = lbase + (size_t)(XT_TASKS + s * (PTILES * 12)) * 1024;
    // A frag (pt, ni, kk) at ab + (pt*12 + ni*3 + kk) KB

    bf16x8 B[6];  // B[mi*3+kk]
    #pragma unroll
    for (int i = 0; i < 6; ++i) B[i] = *(const bf16x8*)(xb + i * 1024);

    bf16x8 A0[12], A1[12];
    #pragma unroll
    for (int i = 0; i < 12; ++i) A0[i] = *(const bf16x8*)(ab + i * 1024);

    const size_t chan = (size_t)b * (NS * NF) + (size_t)s * NF + f;
    float* yrow = y + chan * ((size_t)NP * NXYZ) + (size_t)lr * NXYZ
                    + n32 * 32 + lg * 4;

    #pragma unroll
    for (int pt = 0; pt < PTILES; ++pt) {
        const bf16x8* cur = (pt & 1) ? A1 : A0;   // static after unroll
        bf16x8*       nxt = (pt & 1) ? A0 : A1;

        // Prefetch next tile's A-frags (only ni=0 needed for the tail tile).
        if (pt < PTILES - 1) {
            const char* an = ab + (size_t)(pt + 1) * 12 * 1024;
            const int nload = (pt == PTILES - 2) ? 3 : 12;
            #pragma unroll
            for (int i = 0; i < 12; ++i)
                if (i < nload) nxt[i] = *(const bf16x8*)(an + i * 1024);
        }

        if (pt < PTILES - 1) {
            f32x4 acc[2][4];
            #pragma unroll
            for (int kk = 0; kk < 3; ++kk)
                #pragma unroll
                for (int mi = 0; mi < 2; ++mi)
                    #pragma unroll
                    for (int ni = 0; ni < 4; ++ni)
                        acc[mi][ni] = __builtin_amdgcn_mfma_f32_16x16x32_bf16(
                            B[mi * 3 + kk], cur[ni * 3 + kk],
                            kk ? acc[mi][ni] : (f32x4){0.f, 0.f, 0.f, 0.f},
                            0, 0, 0);
            float* dbase = yrow + (size_t)(pt * MT) * NXYZ;
            #pragma unroll
            for (int ni = 0; ni < 4; ++ni) {
                float* dst = dbase + (size_t)(ni * 16) * NXYZ;
                __builtin_nontemporal_store(acc[0][ni], (f32x4*)dst);
                __builtin_nontemporal_store(acc[1][ni], (f32x4*)(dst + 16));
            }
        } else {
            // Tail tile p0=640: only ni=0, lanes lr<2 valid (p=640,641).
            f32x4 acc0[2];
            #pragma unroll
            for (int kk = 0; kk < 3; ++kk)
                #pragma unroll
                for (int mi = 0; mi < 2; ++mi)
                    acc0[mi] = __builtin_amdgcn_mfma_f32_16x16x32_bf16(
                        B[mi * 3 + kk], cur[kk],
                        kk ? acc0[mi] : (f32x4){0.f, 0.f, 0.f, 0.f},
                        0, 0, 0);
            if (lr < 2) {
                float* dbase = yrow + (size_t)(pt * MT) * NXYZ;
                __builtin_nontemporal_store(acc0[0], (f32x4*)dbase);
                __builtin_nontemporal_store(acc0[1], (f32x4*)(dbase + 16));
            }
        }
    }
}

// ============ Fallback (round-3 structure) if ws too small ================
#define NT 96
#define NTILES 18
#define KP 96
#define ROWB (KP * 2)

__global__ __launch_bounds__(192, 4) void interp_fallback(
    const float* __restrict__ x, const float* __restrict__ Wm,
    float* __restrict__ y)
{
    __shared__ __align__(16) char As[MT * ROWB];
    __shared__ __align__(16) char Bs[NT * ROWB];

    int blk = (int)blockIdx.x;
    const int nt = blk % NTILES; blk /= NTILES;
    const int f  = blk % NF;     blk /= NF;
    const int s  = blk % NS;     blk /= NS;
    const int b  = blk;
    const int tid = (int)threadIdx.x;
    const int n0 = nt * NT;

    {
        const int c  = tid % NT;
        const int kh = tid / NT;
        const float* xp = x + (((size_t)b * NF + f) * (NS * NK) + (size_t)s * NK) * NXYZ
                            + n0 + c;
        const int cs = (c & 7) << 4;
        #pragma unroll
        for (int kk = 0; kk < 48; kk += 8) {
            const int kb = kh * 48 + kk;
            float v[8];
            #pragma unroll
            for (int j = 0; j < 8; ++j) {
                const int k = kb + j;
                v[j] = (k < NK) ? xp[(size_t)k * NXYZ] : 0.f;
            }
            u32x4 u;
            u.x = pack2bf(v[0], v[1]); u.y = pack2bf(v[2], v[3]);
            u.z = pack2bf(v[4], v[5]); u.w = pack2bf(v[6], v[7]);
            *(u32x4*)(Bs + ((c * ROWB + kb * 2) ^ cs)) = u;
        }
    }

    const int lane = tid & 63;
    const int w  = tid / 64;
    const int lr = lane & 15;
    const int lg = lane >> 4;
    const int ls = (lr & 7) << 4;
    const size_t chan = (size_t)b * (NS * NF) + (size_t)s * NF + f;
    float* ybase = y + chan * ((size_t)NP * NXYZ);
    const int xyzbase = n0 + w * 32 + lg * 4;
    const int ar = tid & 63;
    const int akc = tid >> 6;
    const int ars = (ar & 7) << 4;

    for (int pt = 0; pt < PTILES; ++pt) {
        const int p0 = pt * MT;
        __syncthreads();
        {
            const int p = p0 + ar;
            const bool pv = (p < NP);
            const float* wp = Wm + (size_t)s * NK * NP + p;
            #pragma unroll
            for (int kk = 0; kk < 32; kk += 8) {
                const int kb = akc * 32 + kk;
                float v[8];
                #pragma unroll
                for (int j = 0; j < 8; ++j) {
                    const int k = kb + j;
                    v[j] = (pv && (k < NK)) ? wp[(size_t)k * NP] : 0.f;
                }
                u32x4 u;
                u.x = pack2bf(v[0], v[1]); u.y = pack2bf(v[2], v[3]);
                u.z = pack2bf(v[4], v[5]); u.w = pack2bf(v[6], v[7]);
                *(u32x4*)(As + ((ar * ROWB + kb * 2) ^ ars)) = u;
            }
        }
        __syncthreads();

        f32x4 acc[2][4];
        #pragma unroll
        for (int mi = 0; mi < 2; ++mi)
            #pragma unroll
            for (int ni = 0; ni < 4; ++ni)
                acc[mi][ni] = (f32x4){0.f, 0.f, 0.f, 0.f};

        #pragma unroll
        for (int kk = 0; kk < 3; ++kk) {
            const int kbyte = kk * 64 + lg * 16;
            bf16x8 bxyz[2], ap[4];
            #pragma unroll
            for (int mi = 0; mi < 2; ++mi) {
                const int row = w * 32 + mi * 16 + lr;
                bxyz[mi] = *(const bf16x8*)(Bs + ((row * ROWB + kbyte) ^ ls));
            }
            #pragma unroll
            for (int ni = 0; ni < 4; ++ni) {
                const int row = ni * 16 + lr;
                ap[ni] = *(const bf16x8*)(As + ((row * ROWB + kbyte) ^ ls));
            }
            #pragma unroll
            for (int mi = 0; mi < 2; ++mi)
                #pragma unroll
                for (int ni = 0; ni < 4; ++ni)
                    acc[mi][ni] = __builtin_amdgcn_mfma_f32_16x16x32_bf16(
                        bxyz[mi], ap[ni], acc[mi][ni], 0, 0, 0);
        }

        #pragma unroll
        for (int ni = 0; ni < 4; ++ni) {
            const int p = p0 + ni * 16 + lr;
            if (p < NP) {
                float* dst = ybase + (size_t)p * NXYZ + xyzbase;
                __builtin_nontemporal_store(acc[0][ni], (f32x4*)dst);
                __builtin_nontemporal_store(acc[1][ni], (f32x4*)(dst + 16));
            }
        }
    }
}

extern "C" void kernel_launch(void* const* d_in, const int* in_sizes, int n_in,
                              void* d_out, int out_size, void* d_ws, size_t ws_size,
                              hipStream_t stream) {
    (void)in_sizes; (void)n_in; (void)out_size;
    const float* x  = (const float*)d_in[0];
    const float* Wm = (const float*)d_in[1];
    float* y = (float*)d_out;

    const size_t ws_need = (size_t)(XT_TASKS + WT_TASKS) * 1024;  // ~21.8 MB
    if (ws_size >= ws_need) {
        prep_frag<<<(XT_TASKS + WT_TASKS) / 4, 256, 0, stream>>>(x, Wm, (uint32_t*)d_ws);
        gemm_loop<<<64 * 54, 64, 0, stream>>>((const uint32_t*)d_ws, y);
    } else {
        interp_fallback<<<NB * NS * NF * NTILES, 192, 0, stream>>>(x, Wm, y);
    }
}

// Round 7
// 82.112 us; speedup vs baseline: 1.3578x; 1.3578x over previous
//
#include <hip/hip_runtime.h>
#include <cstdint>
#include <cstddef>

// Problem constants
#define NB 2
#define NF 8
#define NS 4
#define NK 90      // real K (dirs per shell)
#define NP 642     // grid vertices
#define NXYZ 1728  // 12*12*12
#define MT 64      // p-tile
#define PTILES 11  // ceil(642/64)
#define NG 108     // xyz 16-groups (1728/16)
#define XT_TASKS (64 * NG * 3)          // 20736 x-fragment blocks (1 KB each)
#define WT_TASKS (NS * PTILES * 4 * 3)  // 528 W-fragment blocks
#define GEMM_TASKS (64 * 54 * PTILES)   // 38016 wave tasks

typedef __attribute__((ext_vector_type(8))) __bf16 bf16x8;
typedef __attribute__((ext_vector_type(4))) float f32x4;
typedef __attribute__((ext_vector_type(4))) uint32_t u32x4;

// RNE pack of two f32 -> u32 holding 2 bf16
__device__ __forceinline__ uint32_t pack2bf(float a, float b) {
    uint32_t ua = __builtin_bit_cast(uint32_t, a);
    uint32_t ub = __builtin_bit_cast(uint32_t, b);
    ua += 0x7FFFu + ((ua >> 16) & 1u);
    ub += 0x7FFFu + ((ub >> 16) & 1u);
    return (ua >> 16) | (ub & 0xFFFF0000u);
}

// ============ Kernel 1: pack x and W into MFMA-fragment-order bf16 blocks.
// Block t (1 KB): 64 lanes x 16 B. Lane (lr=lane&15, lg=lane>>4) holds
// bf16[8] = operand row lr, k = kk*32 + lg*8 .. +8.
// x tasks: t = (e*108 + g)*3 + kk, e = (b*8+f)*4 + s.
// W tasks: XT + ((s*11 + pt)*4 + ni)*3 + kk.
__global__ __launch_bounds__(256) void prep_frag(
    const float* __restrict__ x, const float* __restrict__ Wm,
    uint32_t* __restrict__ ws)
{
    const int tid  = (int)threadIdx.x;
    const int lane = tid & 63;
    const int lr = lane & 15, lg = lane >> 4;
    const int task = (int)blockIdx.x * 4 + (tid >> 6);

    float v[8];
    if (task < XT_TASKS) {
        int t = task;
        const int kk = t % 3;   t /= 3;
        const int g  = t % NG;  t /= NG;
        const int e  = t;                  // 0..63
        const int s = e & 3, bf = e >> 2;
        const float* src = x + (size_t)bf * (NS * NK * NXYZ)
                             + (size_t)s * (NK * NXYZ) + g * 16 + lr;
        #pragma unroll
        for (int j = 0; j < 8; ++j) {
            const int k = kk * 32 + lg * 8 + j;
            v[j] = (k < NK) ? src[(size_t)k * NXYZ] : 0.f;
        }
    } else {
        int t = task - XT_TASKS;
        const int kk = t % 3;      t /= 3;
        const int ni = t % 4;      t /= 4;
        const int pt = t % PTILES; t /= PTILES;
        const int s  = t;                  // 0..3
        const int p = pt * MT + ni * 16 + lr;
        const float* src = Wm + (size_t)s * (NK * NP) + p;
        #pragma unroll
        for (int j = 0; j < 8; ++j) {
            const int k = kk * 32 + lg * 8 + j;
            v[j] = (k < NK && p < NP) ? src[(size_t)k * NP] : 0.f;
        }
    }
    u32x4 u;
    u.x = pack2bf(v[0], v[1]);
    u.y = pack2bf(v[2], v[3]);
    u.z = pack2bf(v[4], v[5]);
    u.w = pack2bf(v[6], v[7]);
    *(u32x4*)((char*)ws + (size_t)task * 1024 + lane * 16) = u;
}

// ============ Kernel 2: barrier-free, LDS-free GEMM (R5 winner), with PLAIN
// stores instead of nontemporal (A/B: NT suspected of defeating L2 write-
// combining -> 1.19x partial-line write amplification seen in R4 counters).
__global__ __launch_bounds__(256, 4) void gemm_frag(
    const uint32_t* __restrict__ ws, float* __restrict__ y)
{
    const int tid  = (int)threadIdx.x;
    const int lane = tid & 63;
    const int lr = lane & 15, lg = lane >> 4;
    int t = (int)blockIdx.x * 4 + (tid >> 6);
    const int pt  = t % PTILES; t /= PTILES;   // pt fastest: 4 waves of a block
    const int n32 = t % 54;     t /= 54;       // share the same B-frags (L1 hit)
    const int e   = t;                          // 0..63
    const int s = e & 3, bf = e >> 2;

    const char* base  = (const char*)ws + (size_t)lane * 16;
    const char* xbase = base + (size_t)((e * NG + n32 * 2) * 3) * 1024;
    const char* abase = base + (size_t)(XT_TASKS + ((s * PTILES + pt) * 4) * 3) * 1024;

    bf16x8 bfr[2][3], afr[4][3];
    #pragma unroll
    for (int mi = 0; mi < 2; ++mi)
        #pragma unroll
        for (int kk = 0; kk < 3; ++kk)
            bfr[mi][kk] = *(const bf16x8*)(xbase + (mi * 3 + kk) * 1024);
    #pragma unroll
    for (int ni = 0; ni < 4; ++ni)
        #pragma unroll
        for (int kk = 0; kk < 3; ++kk)
            afr[ni][kk] = *(const bf16x8*)(abase + (ni * 3 + kk) * 1024);

    f32x4 acc[2][4];
    #pragma unroll
    for (int mi = 0; mi < 2; ++mi)
        #pragma unroll
        for (int ni = 0; ni < 4; ++ni)
            acc[mi][ni] = (f32x4){0.f, 0.f, 0.f, 0.f};

    #pragma unroll
    for (int kk = 0; kk < 3; ++kk)
        #pragma unroll
        for (int mi = 0; mi < 2; ++mi)
            #pragma unroll
            for (int ni = 0; ni < 4; ++ni)
                acc[mi][ni] = __builtin_amdgcn_mfma_f32_16x16x32_bf16(
                    bfr[mi][kk], afr[ni][kk], acc[mi][ni], 0, 0, 0);

    // Store: acc row = xyz (4 consecutive per reg), col = p. PLAIN stores —
    // adjacent acc[0]/acc[1] halves (+64B) should write-combine into full
    // 128B lines in L2 before HBM writeback.
    const int b = bf >> 3, f = bf & 7;
    const size_t chan = (size_t)b * (NS * NF) + (size_t)s * NF + f;
    float* ybase = y + chan * ((size_t)NP * NXYZ) + n32 * 32 + lg * 4;
    #pragma unroll
    for (int ni = 0; ni < 4; ++ni) {
        const int p = pt * MT + ni * 16 + lr;
        if (p < NP) {
            float* dst = ybase + (size_t)p * NXYZ;
            *(f32x4*)dst = acc[0][ni];
            *(f32x4*)(dst + 16) = acc[1][ni];
        }
    }
}

// ============ Fallback (round-3 structure) if ws too small ================
#define NT 96
#define NTILES 18
#define KP 96
#define ROWB (KP * 2)

__global__ __launch_bounds__(192, 4) void interp_fallback(
    const float* __restrict__ x, const float* __restrict__ Wm,
    float* __restrict__ y)
{
    __shared__ __align__(16) char As[MT * ROWB];
    __shared__ __align__(16) char Bs[NT * ROWB];

    int blk = (int)blockIdx.x;
    const int nt = blk % NTILES; blk /= NTILES;
    const int f  = blk % NF;     blk /= NF;
    const int s  = blk % NS;     blk /= NS;
    const int b  = blk;
    const int tid = (int)threadIdx.x;
    const int n0 = nt * NT;

    {
        const int c  = tid % NT;
        const int kh = tid / NT;
        const float* xp = x + (((size_t)b * NF + f) * (NS * NK) + (size_t)s * NK) * NXYZ
                            + n0 + c;
        const int cs = (c & 7) << 4;
        #pragma unroll
        for (int kk = 0; kk < 48; kk += 8) {
            const int kb = kh * 48 + kk;
            float v[8];
            #pragma unroll
            for (int j = 0; j < 8; ++j) {
                const int k = kb + j;
                v[j] = (k < NK) ? xp[(size_t)k * NXYZ] : 0.f;
            }
            u32x4 u;
            u.x = pack2bf(v[0], v[1]); u.y = pack2bf(v[2], v[3]);
            u.z = pack2bf(v[4], v[5]); u.w = pack2bf(v[6], v[7]);
            *(u32x4*)(Bs + ((c * ROWB + kb * 2) ^ cs)) = u;
        }
    }

    const int lane = tid & 63;
    const int w  = tid / 64;
    const int lr = lane & 15;
    const int lg = lane >> 4;
    const int ls = (lr & 7) << 4;
    const size_t chan = (size_t)b * (NS * NF) + (size_t)s * NF + f;
    float* ybase = y + chan * ((size_t)NP * NXYZ);
    const int xyzbase = n0 + w * 32 + lg * 4;
    const int ar = tid & 63;
    const int akc = tid >> 6;
    const int ars = (ar & 7) << 4;

    for (int pt = 0; pt < PTILES; ++pt) {
        const int p0 = pt * MT;
        __syncthreads();
        {
            const int p = p0 + ar;
            const bool pv = (p < NP);
            const float* wp = Wm + (size_t)s * NK * NP + p;
            #pragma unroll
            for (int kk = 0; kk < 32; kk += 8) {
                const int kb = akc * 32 + kk;
                float v[8];
                #pragma unroll
                for (int j = 0; j < 8; ++j) {
                    const int k = kb + j;
                    v[j] = (pv && (k < NK)) ? wp[(size_t)k * NP] : 0.f;
                }
                u32x4 u;
                u.x = pack2bf(v[0], v[1]); u.y = pack2bf(v[2], v[3]);
                u.z = pack2bf(v[4], v[5]); u.w = pack2bf(v[6], v[7]);
                *(u32x4*)(As + ((ar * ROWB + kb * 2) ^ ars)) = u;
            }
        }
        __syncthreads();

        f32x4 acc[2][4];
        #pragma unroll
        for (int mi = 0; mi < 2; ++mi)
            #pragma unroll
            for (int ni = 0; ni < 4; ++ni)
                acc[mi][ni] = (f32x4){0.f, 0.f, 0.f, 0.f};

        #pragma unroll
        for (int kk = 0; kk < 3; ++kk) {
            const int kbyte = kk * 64 + lg * 16;
            bf16x8 bxyz[2], ap[4];
            #pragma unroll
            for (int mi = 0; mi < 2; ++mi) {
                const int row = w * 32 + mi * 16 + lr;
                bxyz[mi] = *(const bf16x8*)(Bs + ((row * ROWB + kbyte) ^ ls));
            }
            #pragma unroll
            for (int ni = 0; ni < 4; ++ni) {
                const int row = ni * 16 + lr;
                ap[ni] = *(const bf16x8*)(As + ((row * ROWB + kbyte) ^ ls));
            }
            #pragma unroll
            for (int mi = 0; mi < 2; ++mi)
                #pragma unroll
                for (int ni = 0; ni < 4; ++ni)
                    acc[mi][ni] = __builtin_amdgcn_mfma_f32_16x16x32_bf16(
                        bxyz[mi], ap[ni], acc[mi][ni], 0, 0, 0);
        }

        #pragma unroll
        for (int ni = 0; ni < 4; ++ni) {
            const int p = p0 + ni * 16 + lr;
            if (p < NP) {
                float* dst = ybase + (size_t)p * NXYZ + xyzbase;
                *(f32x4*)dst = acc[0][ni];
                *(f32x4*)(dst + 16) = acc[1][ni];
            }
        }
    }
}

extern "C" void kernel_launch(void* const* d_in, const int* in_sizes, int n_in,
                              void* d_out, int out_size, void* d_ws, size_t ws_size,
                              hipStream_t stream) {
    (void)in_sizes; (void)n_in; (void)out_size;
    const float* x  = (const float*)d_in[0];
    const float* Wm = (const float*)d_in[1];
    float* y = (float*)d_out;

    const size_t ws_need = (size_t)(XT_TASKS + WT_TASKS) * 1024;  // ~21.8 MB
    if (ws_size >= ws_need) {
        prep_frag<<<(XT_TASKS + WT_TASKS) / 4, 256, 0, stream>>>(x, Wm, (uint32_t*)d_ws);
        gemm_frag<<<GEMM_TASKS / 4, 256, 0, stream>>>((const uint32_t*)d_ws, y);
    } else {
        interp_fallback<<<NB * NS * NF * NTILES, 192, 0, stream>>>(x, Wm, y);
    }
}